// Round 2
// baseline (24.126 us; speedup 1.0000x reference)
//
#include <hip/hip_runtime.h>

// Blur+downsample: (32,512,512,3) f32 NHWC, 2x2 depthwise kernel, stride 2, SAME.
// SAME pad is 0 (512 even, k=2, s=2) -> non-overlapping weighted 2x2 pool:
// out[b,oh,ow,c] = k00*x[2oh,2ow,c] + k01*x[2oh,2ow+1,c]
//                + k10*x[2oh+1,2ow,c] + k11*x[2oh+1,2ow+1,c]
//
// Direct-register version (no LDS, no barrier): each thread computes 4 output
// pixels = 12 contiguous floats (16B-aligned). It reads 2 rows x 6 float4
// (16B-aligned, 96B lane stride -> contiguous 6KB span per wave, L1 merges),
// and writes 3 float4. Zero data reuse exists, so pure streaming is optimal.

#define ROWF 1536          // floats per input row (512*3)
#define NBLOCKS 2048       // 524288 threads * 12 floats = 6291456 out floats

__global__ __launch_bounds__(256) void blur_ds_kernel(
    const float* __restrict__ x, const float* __restrict__ kern,
    float* __restrict__ out) {
  const int g = blockIdx.x * 256 + threadIdx.x;
  const int r = g >> 6;     // combined (b*256 + oh) output-row id, 0..8191
  const int lane = g & 63;  // 64 threads per output row, 4 pixels each

  const float k00 = kern[0];
  const float k01 = kern[1];
  const float k10 = kern[2];
  const float k11 = kern[3];

  // input rows 2*oh, 2*oh+1 of image b == rows 2r, 2r+1 of the flat row array
  const float4* s0 = (const float4*)(x + (size_t)r * (2 * ROWF) + lane * 24);
  const float4* s1 = s0 + (ROWF / 4);

  float af[24], bf[24];  // all indices compile-time after unroll -> registers
#pragma unroll
  for (int j = 0; j < 6; ++j) {
    const float4 v = s0[j];
    af[4 * j + 0] = v.x; af[4 * j + 1] = v.y;
    af[4 * j + 2] = v.z; af[4 * j + 3] = v.w;
  }
#pragma unroll
  for (int j = 0; j < 6; ++j) {
    const float4 v = s1[j];
    bf[4 * j + 0] = v.x; bf[4 * j + 1] = v.y;
    bf[4 * j + 2] = v.z; bf[4 * j + 3] = v.w;
  }

  float of[12];
#pragma unroll
  for (int p = 0; p < 4; ++p) {
#pragma unroll
    for (int c = 0; c < 3; ++c) {
      const int gi = 6 * p + c;
      of[3 * p + c] = k00 * af[gi] + k01 * af[gi + 3] +
                      k10 * bf[gi] + k11 * bf[gi + 3];
    }
  }

  float4* o4 = (float4*)(out + (size_t)g * 12);  // 48B/thread, 16B-aligned
  o4[0] = make_float4(of[0], of[1], of[2], of[3]);
  o4[1] = make_float4(of[4], of[5], of[6], of[7]);
  o4[2] = make_float4(of[8], of[9], of[10], of[11]);
}

extern "C" void kernel_launch(void* const* d_in, const int* in_sizes, int n_in,
                              void* d_out, int out_size, void* d_ws,
                              size_t ws_size, hipStream_t stream) {
  const float* x = (const float*)d_in[0];
  const float* kern = (const float*)d_in[1];
  float* out = (float*)d_out;

  blur_ds_kernel<<<NBLOCKS, 256, 0, stream>>>(x, kern, out);
}